// Round 2
// baseline (279.789 us; speedup 1.0000x reference)
//
#include <hip/hip_runtime.h>
#include <math.h>

#define NROWS 8192
#define NK    4096
#define NE    64
#define NSEG  8   // K partial segments written to workspace

// ---------------------------------------------------------------------------
// Kernel 1: logits = x @ W^T, fp32 vector FMA.
// grid = 256 blocks (128 row-groups x 2 K-halves), block = 512 (8 waves).
// Wave wv: rows rg*64+lane (lane = row), all 64 experts, k in [h*2048+wv*256, +256).
// W[e][k] is wave-uniform -> scalar s_load path; x streamed with next-tile
// register prefetch. One 8->4 LDS pair-reduce; waves 0..3 write partial
// logits for segment s = h*4+wv to workspace part[s][row][e].
// __launch_bounds__(512,1): allow up to 512 VGPR so acc[64] is NOT spilled
// (round-1 compiler chose 52 VGPR and scratch-spilled the accumulator).
// ---------------------------------------------------------------------------
__global__ __launch_bounds__(512, 1) void k_gemm(const float* __restrict__ x,
                                                 const float* __restrict__ W,
                                                 float* __restrict__ part) {
  __shared__ float red[4][64][65];  // stride-65: conflict-free
  const int tid  = threadIdx.x;
  const int lane = tid & 63;
  const int wv   = tid >> 6;          // 0..7
  const int rg   = blockIdx.x >> 1;   // 0..127
  const int h    = blockIdx.x & 1;    // K-half
  const int row  = rg * 64 + lane;
  const int k0   = h * 2048 + wv * 256;

  const float* __restrict__ xp = x + (size_t)row * NK + k0;
  const float* __restrict__ wp = W + k0;   // wave-uniform base

  float acc[NE];
#pragma unroll
  for (int e = 0; e < NE; ++e) acc[e] = 0.f;

  // current x tile in registers; prefetch next tile each iteration
  float4 c0 = ((const float4*)xp)[0];
  float4 c1 = ((const float4*)xp)[1];
  float4 c2 = ((const float4*)xp)[2];
  float4 c3 = ((const float4*)xp)[3];

#pragma unroll 1
  for (int t = 0; t < 16; ++t) {   // 16 tiles of 16 k
    const float* xn = xp + ((t < 15) ? (t + 1) * 16 : t * 16);
    float4 n0 = ((const float4*)xn)[0];
    float4 n1 = ((const float4*)xn)[1];
    float4 n2 = ((const float4*)xn)[2];
    float4 n3 = ((const float4*)xn)[3];

    const float xr[16] = {c0.x, c0.y, c0.z, c0.w, c1.x, c1.y, c1.z, c1.w,
                          c2.x, c2.y, c2.z, c2.w, c3.x, c3.y, c3.z, c3.w};
    const float* wt = wp + t * 16;
#pragma unroll
    for (int e = 0; e < NE; ++e) {
      const float* wr = wt + (size_t)e * NK;  // uniform -> s_load_dwordx16
      float s0 = xr[0] * wr[0];
      float s1 = xr[8] * wr[8];
#pragma unroll
      for (int j = 1; j < 8; ++j) {
        s0 = fmaf(xr[j], wr[j], s0);
        s1 = fmaf(xr[j + 8], wr[j + 8], s1);
      }
      acc[e] += (s0 + s1);
    }
    c0 = n0; c1 = n1; c2 = n2; c3 = n3;
  }

  // ---- single 8->4 pair reduce; waves 0..3 own segments h*4+wv ----
  if (wv >= 4) {
#pragma unroll
    for (int e = 0; e < NE; ++e) red[wv - 4][lane][e] = acc[e];
  }
  __syncthreads();
  if (wv < 4) {
#pragma unroll
    for (int e = 0; e < NE; ++e) acc[e] += red[wv][lane][e];
    float* dst = part + ((size_t)(h * 4 + wv) * NROWS + row) * NE;
#pragma unroll
    for (int e = 0; e < NE; e += 4) {
      float4 v = {acc[e], acc[e + 1], acc[e + 2], acc[e + 3]};
      *(float4*)(dst + e) = v;
    }
  }
}

// ---------------------------------------------------------------------------
// Kernel 2: sum 8 K-segment partials (pairwise tree) -> softmax over 64
// experts (lane = expert) -> stable top-2 -> renorm softmax -> outputs;
// importance accumulated per block, one atomicAdd per expert.
// grid = 256, block = 256 (4 waves), each wave handles 8 rows.
// ---------------------------------------------------------------------------
__global__ __launch_bounds__(256) void k_softmax(const float* __restrict__ part,
                                                 float* __restrict__ out,
                                                 float* __restrict__ imp) {
  __shared__ float simp[4][64];
  const int tid  = threadIdx.x;
  const int lane = tid & 63;
  const int wv   = tid >> 6;
  const int rbase = blockIdx.x * 32 + wv * 8;
  float impacc = 0.f;

  for (int i = 0; i < 8; ++i) {
    const int row = rbase + i;
    float v[NSEG];
#pragma unroll
    for (int s = 0; s < NSEG; ++s)
      v[s] = part[((size_t)s * NROWS + row) * NE + lane];
#pragma unroll
    for (int st = 1; st < NSEG; st <<= 1)
#pragma unroll
      for (int s = 0; s < NSEG; s += 2 * st) v[s] += v[s + st];
    const float lg = v[0];

    // softmax across the wave (64 lanes = 64 experts)
    float m = lg;
#pragma unroll
    for (int d = 1; d < 64; d <<= 1) m = fmaxf(m, __shfl_xor(m, d));
    float p = expf(lg - m);
    float s = p;
#pragma unroll
    for (int d = 1; d < 64; d <<= 1) s += __shfl_xor(s, d);
    const float gate = p / s;
    impacc += gate;

    // top-2 via packed key: (gate bits << 32) | (63 - e); gates > 0 so float
    // bit-order == value order; ties -> lower expert index wins (jax stable).
    const unsigned long long key =
        ((unsigned long long)__float_as_uint(gate) << 32) | (unsigned)(63 - lane);
    unsigned long long k1 = key;
#pragma unroll
    for (int d = 1; d < 64; d <<= 1) {
      unsigned long long o = __shfl_xor(k1, d);
      if (o > k1) k1 = o;
    }
    const int e1 = 63 - (int)(k1 & 63ull);
    unsigned long long k2 = (lane == e1) ? 0ull : key;
#pragma unroll
    for (int d = 1; d < 64; d <<= 1) {
      unsigned long long o = __shfl_xor(k2, d);
      if (o > k2) k2 = o;
    }
    const int e2 = 63 - (int)(k2 & 63ull);

    if (lane == 0) {
      const float g1 = __uint_as_float((unsigned)(k1 >> 32));
      const float g2 = __uint_as_float((unsigned)(k2 >> 32));
      const float tt  = expf(g2 - g1);          // g1 >= g2
      const float inv = 1.f / (1.f + tt);
      out[(size_t)row * 2]     = inv;            // combine_weights
      out[(size_t)row * 2 + 1] = tt * inv;
      out[(size_t)NROWS * 2 + row * 2]     = (float)e1;  // indices as float
      out[(size_t)NROWS * 2 + row * 2 + 1] = (float)e2;
    }
  }

  simp[wv][lane] = impacc;
  __syncthreads();
  if (tid < NE) {
    const float v = simp[0][tid] + simp[1][tid] + simp[2][tid] + simp[3][tid];
    atomicAdd(&imp[tid], v);
  }
}

// ---------------------------------------------------------------------------
// Kernel 3: aux loss from importance vector (1 wave).
// ---------------------------------------------------------------------------
__global__ void k_aux(const float* __restrict__ imp, float* __restrict__ out) {
  const int lane = threadIdx.x;  // 64 threads
  const float v = imp[lane];
  float s = v;
#pragma unroll
  for (int d = 1; d < 64; d <<= 1) s += __shfl_xor(s, d);
  const float mean = s / 64.f;
  const float dv = v - mean;
  float sq = dv * dv;
#pragma unroll
  for (int d = 1; d < 64; d <<= 1) sq += __shfl_xor(sq, d);
  const float stdv = sqrtf(sq / 63.f);  // unbiased (E-1)
  const float r = stdv / (mean + 1e-6f);
  if (lane == 0) out[(size_t)NROWS * 4] = r * r;  // d_out[32768]
}

__global__ void k_zero(float* __restrict__ imp) { imp[threadIdx.x] = 0.f; }

// ---------------------------------------------------------------------------
extern "C" void kernel_launch(void* const* d_in, const int* in_sizes, int n_in,
                              void* d_out, int out_size, void* d_ws, size_t ws_size,
                              hipStream_t stream) {
  const float* x = (const float*)d_in[0];
  const float* W = (const float*)d_in[1];
  float* out  = (float*)d_out;
  float* part = (float*)d_ws;                          // 8*8192*64 f32 = 16 MB
  float* imp  = part + (size_t)NSEG * NROWS * NE;      // 64 f32

  hipLaunchKernelGGL(k_zero,    dim3(1),   dim3(64),  0, stream, imp);
  hipLaunchKernelGGL(k_gemm,    dim3(256), dim3(512), 0, stream, x, W, part);
  hipLaunchKernelGGL(k_softmax, dim3(256), dim3(256), 0, stream, part, out, imp);
  hipLaunchKernelGGL(k_aux,     dim3(1),   dim3(64),  0, stream, imp, out);
}

// Round 3
// 182.313 us; speedup vs baseline: 1.5347x; 1.5347x over previous
//
#include <hip/hip_runtime.h>
#include <math.h>

#define NROWS 8192
#define NK    4096
#define NE    64
#define NSEG  4    // K segments (1024 k each), one per block

// ---------------------------------------------------------------------------
// Kernel 1: partial logits = x @ W^T over one K-segment.
// grid = 512 (128 row-groups x 4 K-segments), block = 512 (8 waves).
// lane = row within 64-row group; wave wv owns experts [wv*8, wv*8+8) -> acc[8]
// (8 accumulators/thread: spill-proof, unlike rounds 1-2's acc[64]).
// x: staged per block into LDS (double-buffered, XOR-swizzled float4 tiles,
//    conflict-free ds_read_b128 / ds_write_b128), shared by all 8 waves.
// W: wave-uniform addresses via readfirstlane -> scalar s_load path; VALU does
//    nearly pure v_fma_f32 (32 FMA per ds_read_b128).
// ---------------------------------------------------------------------------
__global__ __launch_bounds__(512, 1) void k_gemm(const float* __restrict__ x,
                                                 const float* __restrict__ W,
                                                 float* __restrict__ part) {
  __shared__ float4 xs4[2][64][32];   // 64 KB, double-buffered 64rows x 128k
  const int tid   = threadIdx.x;
  const int lane  = tid & 63;
  const int wv_u  = __builtin_amdgcn_readfirstlane(tid >> 6);  // 0..7 uniform
  const int rg    = blockIdx.x >> 2;    // 0..127
  const int seg   = blockIdx.x & 3;     // K-segment
  const int kbase = seg * 1024;
  const int row   = rg * 64 + lane;

  // staging geometry: thread handles float4 index f4 = i*512 + tid, i=0..3
  //   -> r = i*16 + (tid>>5), k4 = tid&31  (coalesced global, swizzled LDS)
  const int sr  = tid >> 5;        // row offset within 16-row sweep
  const int sk4 = tid & 31;        // float4 column
  const int ssw = sr & 7;          // swizzle XOR for this thread's rows
  const float* __restrict__ xg =
      x + ((size_t)(rg * 64 + sr)) * NK + kbase + sk4 * 4;

  float acc[8];
#pragma unroll
  for (int e = 0; e < 8; ++e) acc[e] = 0.f;

  float4 pf[4];
  // prologue: load chunk 0 into regs, write to buf 0
#pragma unroll
  for (int i = 0; i < 4; ++i)
    pf[i] = *(const float4*)(xg + (size_t)i * 16 * NK);
#pragma unroll
  for (int i = 0; i < 4; ++i)
    xs4[0][i * 16 + sr][sk4 ^ ssw] = pf[i];

#pragma unroll 1
  for (int c = 0; c < 8; ++c) {       // 8 chunks of 128 k
    if (c < 7) {                      // prefetch next chunk to regs
      const float* xn = xg + (c + 1) * 128;
#pragma unroll
      for (int i = 0; i < 4; ++i)
        pf[i] = *(const float4*)(xn + (size_t)i * 16 * NK);
    }
    __syncthreads();                  // buf[c&1] fully written; prev compute done

    const int buf = c & 1;
    const float* __restrict__ Wc = W + (size_t)(wv_u * 8) * NK + kbase + c * 128;
#pragma unroll 4
    for (int q = 0; q < 32; ++q) {    // 32 k-quads
      const float4 xv = xs4[buf][lane][q ^ (lane & 7)];
      const float* wq = Wc + q * 4;   // wave-uniform -> s_load
#pragma unroll
      for (int e = 0; e < 8; ++e) {
        const float* wr = wq + (size_t)e * NK;
        acc[e] = fmaf(xv.x, wr[0], acc[e]);
        acc[e] = fmaf(xv.y, wr[1], acc[e]);
        acc[e] = fmaf(xv.z, wr[2], acc[e]);
        acc[e] = fmaf(xv.w, wr[3], acc[e]);
      }
    }

    if (c < 7) {                      // write prefetched chunk to other buffer
      const int nb = (c + 1) & 1;
#pragma unroll
      for (int i = 0; i < 4; ++i)
        xs4[nb][i * 16 + sr][sk4 ^ ssw] = pf[i];
    }
  }

  // epilogue: thread owns (row, experts wv_u*8..+8) for this segment
  float* dst = part + ((size_t)seg * NROWS + row) * NE + wv_u * 8;
  float4 v0 = {acc[0], acc[1], acc[2], acc[3]};
  float4 v1 = {acc[4], acc[5], acc[6], acc[7]};
  *(float4*)(dst)     = v0;
  *(float4*)(dst + 4) = v1;
}

// ---------------------------------------------------------------------------
// Kernel 2: sum 4 K-segment partials (pairwise) -> softmax over 64 experts
// (lane = expert) -> stable top-2 (lowest-index tie-break) -> renorm softmax
// -> outputs; importance accumulated per block, one atomicAdd per expert.
// grid = 256, block = 256 (4 waves), each wave handles 8 rows.
// ---------------------------------------------------------------------------
__global__ __launch_bounds__(256) void k_softmax(const float* __restrict__ part,
                                                 float* __restrict__ out,
                                                 float* __restrict__ imp) {
  __shared__ float simp[4][64];
  const int tid  = threadIdx.x;
  const int lane = tid & 63;
  const int wv   = tid >> 6;
  const int rbase = blockIdx.x * 32 + wv * 8;
  float impacc = 0.f;

  for (int i = 0; i < 8; ++i) {
    const int row = rbase + i;
    float v0 = part[((size_t)0 * NROWS + row) * NE + lane];
    float v1 = part[((size_t)1 * NROWS + row) * NE + lane];
    float v2 = part[((size_t)2 * NROWS + row) * NE + lane];
    float v3 = part[((size_t)3 * NROWS + row) * NE + lane];
    const float lg = (v0 + v1) + (v2 + v3);

    // softmax across the wave (64 lanes = 64 experts)
    float m = lg;
#pragma unroll
    for (int d = 1; d < 64; d <<= 1) m = fmaxf(m, __shfl_xor(m, d));
    float p = expf(lg - m);
    float s = p;
#pragma unroll
    for (int d = 1; d < 64; d <<= 1) s += __shfl_xor(s, d);
    const float gate = p / s;
    impacc += gate;

    // top-2 via packed key: (gate bits << 32) | (63 - e); gates > 0 so float
    // bit-order == value order; ties -> lower expert index wins (jax stable).
    const unsigned long long key =
        ((unsigned long long)__float_as_uint(gate) << 32) | (unsigned)(63 - lane);
    unsigned long long k1 = key;
#pragma unroll
    for (int d = 1; d < 64; d <<= 1) {
      unsigned long long o = __shfl_xor(k1, d);
      if (o > k1) k1 = o;
    }
    const int e1 = 63 - (int)(k1 & 63ull);
    unsigned long long k2 = (lane == e1) ? 0ull : key;
#pragma unroll
    for (int d = 1; d < 64; d <<= 1) {
      unsigned long long o = __shfl_xor(k2, d);
      if (o > k2) k2 = o;
    }
    const int e2 = 63 - (int)(k2 & 63ull);

    if (lane == 0) {
      const float g1 = __uint_as_float((unsigned)(k1 >> 32));
      const float g2 = __uint_as_float((unsigned)(k2 >> 32));
      const float tt  = expf(g2 - g1);          // g1 >= g2
      const float inv = 1.f / (1.f + tt);
      out[(size_t)row * 2]     = inv;            // combine_weights
      out[(size_t)row * 2 + 1] = tt * inv;
      out[(size_t)NROWS * 2 + row * 2]     = (float)e1;  // indices as float
      out[(size_t)NROWS * 2 + row * 2 + 1] = (float)e2;
    }
  }

  simp[wv][lane] = impacc;
  __syncthreads();
  if (tid < NE) {
    const float v = simp[0][tid] + simp[1][tid] + simp[2][tid] + simp[3][tid];
    atomicAdd(&imp[tid], v);
  }
}

// ---------------------------------------------------------------------------
// Kernel 3: aux loss from importance vector (1 wave).
// ---------------------------------------------------------------------------
__global__ void k_aux(const float* __restrict__ imp, float* __restrict__ out) {
  const int lane = threadIdx.x;  // 64 threads
  const float v = imp[lane];
  float s = v;
#pragma unroll
  for (int d = 1; d < 64; d <<= 1) s += __shfl_xor(s, d);
  const float mean = s / 64.f;
  const float dv = v - mean;
  float sq = dv * dv;
#pragma unroll
  for (int d = 1; d < 64; d <<= 1) sq += __shfl_xor(sq, d);
  const float stdv = sqrtf(sq / 63.f);  // unbiased (E-1)
  const float r = stdv / (mean + 1e-6f);
  if (lane == 0) out[(size_t)NROWS * 4] = r * r;  // d_out[32768]
}

__global__ void k_zero(float* __restrict__ imp) { imp[threadIdx.x] = 0.f; }

// ---------------------------------------------------------------------------
extern "C" void kernel_launch(void* const* d_in, const int* in_sizes, int n_in,
                              void* d_out, int out_size, void* d_ws, size_t ws_size,
                              hipStream_t stream) {
  const float* x = (const float*)d_in[0];
  const float* W = (const float*)d_in[1];
  float* out  = (float*)d_out;
  float* part = (float*)d_ws;                          // 4*8192*64 f32 = 8 MB
  float* imp  = part + (size_t)NSEG * NROWS * NE;      // 64 f32

  hipLaunchKernelGGL(k_zero,    dim3(1),   dim3(64),  0, stream, imp);
  hipLaunchKernelGGL(k_gemm,    dim3(512), dim3(512), 0, stream, x, W, part);
  hipLaunchKernelGGL(k_softmax, dim3(256), dim3(256), 0, stream, part, out, imp);
  hipLaunchKernelGGL(k_aux,     dim3(1),   dim3(64),  0, stream, imp, out);
}

// Round 4
// 68.088 us; speedup vs baseline: 4.1092x; 2.6776x over previous
//
#include <hip/hip_runtime.h>
#include <math.h>

#define NROWS 8192
#define NK    4096
#define NE    64
#define NSEG  4    // K segments of 1024, one per block

typedef _Float16 f16x8 __attribute__((ext_vector_type(8)));  // 4 VGPRs
typedef float    f32x4 __attribute__((ext_vector_type(4)));

// ---------------------------------------------------------------------------
// Kernel 0: arrange W into MFMA-fragment-linear f16 hi/lo arrays.
// Warr element ((ksg*4 + nt)*64 + lane)*8 + j  holds
//   f16( W[nt*16 + (lane&15)][ksg*32 + (lane>>4)*8 + j] )
// so a B-fragment load in k_gemm is one fully-coalesced 16B/lane read.
// ---------------------------------------------------------------------------
__global__ __launch_bounds__(256) void k_wcvt(const float* __restrict__ W,
                                              _Float16* __restrict__ Whi,
                                              _Float16* __restrict__ Wlo) {
  const int idx = blockIdx.x * 256 + threadIdx.x;   // 0 .. 262143
  const int j    = idx & 7;
  const int lane = (idx >> 3) & 63;
  const int nt   = (idx >> 9) & 3;
  const int ksg  = idx >> 11;                        // 0..127
  const int e = nt * 16 + (lane & 15);
  const int k = ksg * 32 + (lane >> 4) * 8 + j;
  const float w = W[(size_t)e * NK + k];
  const _Float16 wh = (_Float16)w;
  const _Float16 wl = (_Float16)(w - (float)wh);
  Whi[idx] = wh;
  Wlo[idx] = wl;
}

// ---------------------------------------------------------------------------
// Kernel 1: partial logits via MFMA f16 hi/lo split (fp32-equivalent).
// grid = 512 (128 M-tiles x 4 K-segments), block = 256 (4 waves).
// Wave wv: rows mt*64 + wv*16 .. +16, all 64 experts (4 N-tiles), 1024 k.
// A: built in-register from global f32 (each x element read & converted once).
// B: fragment-linear f16 from Whi/Wlo (L2-resident, 1KB coalesced per frag).
// No LDS, no barriers, acc = 4 x f32x4 -> no spill pressure.
// D layout (verified m89): col = lane&15, row = (lane>>4)*4 + reg.
// ---------------------------------------------------------------------------
__global__ __launch_bounds__(256) void k_gemm(const float* __restrict__ x,
                                              const _Float16* __restrict__ Whi,
                                              const _Float16* __restrict__ Wlo,
                                              float* __restrict__ part) {
  const int tid  = threadIdx.x;
  const int lane = tid & 63;
  const int wv   = tid >> 6;          // 0..3
  const int mt   = blockIdx.x >> 2;   // 0..127
  const int seg  = blockIdx.x & 3;    // K-segment
  const int l15  = lane & 15;
  const int lhi  = lane >> 4;
  const int rbase = mt * 64 + wv * 16;
  const int k0    = seg * 1024;

  const float* __restrict__ xp = x + (size_t)(rbase + l15) * NK + k0 + lhi * 8;

  f32x4 acc[4];
#pragma unroll
  for (int nt = 0; nt < 4; ++nt) acc[nt] = (f32x4){0.f, 0.f, 0.f, 0.f};

#pragma unroll 4
  for (int ks = 0; ks < 32; ++ks) {   // 32 K-steps of 32
    // ---- A fragment: 8 f32 -> (hi, lo) f16x8, all indices compile-time ----
    const float4 a0 = *(const float4*)(xp + ks * 32);
    const float4 a1 = *(const float4*)(xp + ks * 32 + 4);
    f16x8 ah, al;
    ah[0] = (_Float16)a0.x; al[0] = (_Float16)(a0.x - (float)ah[0]);
    ah[1] = (_Float16)a0.y; al[1] = (_Float16)(a0.y - (float)ah[1]);
    ah[2] = (_Float16)a0.z; al[2] = (_Float16)(a0.z - (float)ah[2]);
    ah[3] = (_Float16)a0.w; al[3] = (_Float16)(a0.w - (float)ah[3]);
    ah[4] = (_Float16)a1.x; al[4] = (_Float16)(a1.x - (float)ah[4]);
    ah[5] = (_Float16)a1.y; al[5] = (_Float16)(a1.y - (float)ah[5]);
    ah[6] = (_Float16)a1.z; al[6] = (_Float16)(a1.z - (float)ah[6]);
    ah[7] = (_Float16)a1.w; al[7] = (_Float16)(a1.w - (float)ah[7]);

    // ---- B fragments: fragment-linear, 16B/lane coalesced ----
    const size_t boff = ((size_t)((seg * 32 + ks) * 4) * 64 + lane) * 8;
    f16x8 bhv[4], blv[4];
#pragma unroll
    for (int nt = 0; nt < 4; ++nt) {
      bhv[nt] = *(const f16x8*)(Whi + boff + nt * 512);
      blv[nt] = *(const f16x8*)(Wlo + boff + nt * 512);
    }
    // ---- 12 MFMAs, dependency distance 4 per accumulator ----
#pragma unroll
    for (int nt = 0; nt < 4; ++nt)
      acc[nt] = __builtin_amdgcn_mfma_f32_16x16x32_f16(ah, bhv[nt], acc[nt], 0, 0, 0);
#pragma unroll
    for (int nt = 0; nt < 4; ++nt)
      acc[nt] = __builtin_amdgcn_mfma_f32_16x16x32_f16(ah, blv[nt], acc[nt], 0, 0, 0);
#pragma unroll
    for (int nt = 0; nt < 4; ++nt)
      acc[nt] = __builtin_amdgcn_mfma_f32_16x16x32_f16(al, bhv[nt], acc[nt], 0, 0, 0);
  }

  // ---- epilogue: D col = lane&15, row = (lane>>4)*4 + reg ----
  float* dst = part + ((size_t)seg * NROWS + rbase) * NE;
#pragma unroll
  for (int nt = 0; nt < 4; ++nt)
#pragma unroll
    for (int r = 0; r < 4; ++r)
      dst[(size_t)(lhi * 4 + r) * NE + nt * 16 + l15] = acc[nt][r];
}

// ---------------------------------------------------------------------------
// Kernel 2: sum 4 K-segment partials (pairwise) -> softmax over 64 experts
// (lane = expert) -> stable top-2 (lowest-index tie-break) -> renorm softmax
// -> outputs; importance accumulated per block, one atomicAdd per expert.
// ---------------------------------------------------------------------------
__global__ __launch_bounds__(256) void k_softmax(const float* __restrict__ part,
                                                 float* __restrict__ out,
                                                 float* __restrict__ imp) {
  __shared__ float simp[4][64];
  const int tid  = threadIdx.x;
  const int lane = tid & 63;
  const int wv   = tid >> 6;
  const int rbase = blockIdx.x * 32 + wv * 8;
  float impacc = 0.f;

  for (int i = 0; i < 8; ++i) {
    const int row = rbase + i;
    float v0 = part[((size_t)0 * NROWS + row) * NE + lane];
    float v1 = part[((size_t)1 * NROWS + row) * NE + lane];
    float v2 = part[((size_t)2 * NROWS + row) * NE + lane];
    float v3 = part[((size_t)3 * NROWS + row) * NE + lane];
    const float lg = (v0 + v1) + (v2 + v3);

    float m = lg;
#pragma unroll
    for (int d = 1; d < 64; d <<= 1) m = fmaxf(m, __shfl_xor(m, d));
    float p = expf(lg - m);
    float s = p;
#pragma unroll
    for (int d = 1; d < 64; d <<= 1) s += __shfl_xor(s, d);
    const float gate = p / s;
    impacc += gate;

    const unsigned long long key =
        ((unsigned long long)__float_as_uint(gate) << 32) | (unsigned)(63 - lane);
    unsigned long long k1 = key;
#pragma unroll
    for (int d = 1; d < 64; d <<= 1) {
      unsigned long long o = __shfl_xor(k1, d);
      if (o > k1) k1 = o;
    }
    const int e1 = 63 - (int)(k1 & 63ull);
    unsigned long long k2 = (lane == e1) ? 0ull : key;
#pragma unroll
    for (int d = 1; d < 64; d <<= 1) {
      unsigned long long o = __shfl_xor(k2, d);
      if (o > k2) k2 = o;
    }
    const int e2 = 63 - (int)(k2 & 63ull);

    if (lane == 0) {
      const float g1 = __uint_as_float((unsigned)(k1 >> 32));
      const float g2 = __uint_as_float((unsigned)(k2 >> 32));
      const float tt  = expf(g2 - g1);          // g1 >= g2
      const float inv = 1.f / (1.f + tt);
      out[(size_t)row * 2]     = inv;
      out[(size_t)row * 2 + 1] = tt * inv;
      out[(size_t)NROWS * 2 + row * 2]     = (float)e1;
      out[(size_t)NROWS * 2 + row * 2 + 1] = (float)e2;
    }
  }

  simp[wv][lane] = impacc;
  __syncthreads();
  if (tid < NE) {
    const float v = simp[0][tid] + simp[1][tid] + simp[2][tid] + simp[3][tid];
    atomicAdd(&imp[tid], v);
  }
}

// ---------------------------------------------------------------------------
// Kernel 3: aux loss from importance vector (1 wave).
// ---------------------------------------------------------------------------
__global__ void k_aux(const float* __restrict__ imp, float* __restrict__ out) {
  const int lane = threadIdx.x;  // 64 threads
  const float v = imp[lane];
  float s = v;
#pragma unroll
  for (int d = 1; d < 64; d <<= 1) s += __shfl_xor(s, d);
  const float mean = s / 64.f;
  const float dv = v - mean;
  float sq = dv * dv;
#pragma unroll
  for (int d = 1; d < 64; d <<= 1) sq += __shfl_xor(sq, d);
  const float stdv = sqrtf(sq / 63.f);  // unbiased (E-1)
  const float r = stdv / (mean + 1e-6f);
  if (lane == 0) out[(size_t)NROWS * 4] = r * r;  // d_out[32768]
}

__global__ void k_zero(float* __restrict__ imp) { imp[threadIdx.x] = 0.f; }

// ---------------------------------------------------------------------------
extern "C" void kernel_launch(void* const* d_in, const int* in_sizes, int n_in,
                              void* d_out, int out_size, void* d_ws, size_t ws_size,
                              hipStream_t stream) {
  const float* x = (const float*)d_in[0];
  const float* W = (const float*)d_in[1];
  float* out  = (float*)d_out;
  float* part = (float*)d_ws;                           // 4*8192*64 f32 = 8 MB
  _Float16* Whi = (_Float16*)(part + (size_t)NSEG * NROWS * NE);  // 512 KB
  _Float16* Wlo = Whi + (size_t)NE * NK;                          // 512 KB
  float* imp  = (float*)(Wlo + (size_t)NE * NK);                  // 64 f32

  hipLaunchKernelGGL(k_zero,    dim3(1),    dim3(64),  0, stream, imp);
  hipLaunchKernelGGL(k_wcvt,    dim3(1024), dim3(256), 0, stream, W, Whi, Wlo);
  hipLaunchKernelGGL(k_gemm,    dim3(512),  dim3(256), 0, stream, x, Whi, Wlo, part);
  hipLaunchKernelGGL(k_softmax, dim3(256),  dim3(256), 0, stream, part, out, imp);
  hipLaunchKernelGGL(k_aux,     dim3(1),    dim3(64),  0, stream, imp, out);
}

// Round 5
// 60.405 us; speedup vs baseline: 4.6319x; 1.1272x over previous
//
#include <hip/hip_runtime.h>
#include <math.h>

#define NROWS 8192
#define NK    4096
#define NE    64
#define NSEG  8    // K segments of 512, one per block

typedef _Float16 f16x8 __attribute__((ext_vector_type(8)));  // 4 VGPRs
typedef float    f32x4 __attribute__((ext_vector_type(4)));

// ---------------------------------------------------------------------------
// Kernel 0: arrange W into MFMA-fragment-linear f16 hi/lo arrays + zero imp.
// Element ((ksg*4 + nt)*64 + lane)*8 + j  holds
//   f16( W[nt*16 + (lane&15)][ksg*32 + (lane>>4)*8 + j] ),  ksg = 0..127.
// ---------------------------------------------------------------------------
__global__ __launch_bounds__(256) void k_prep(const float* __restrict__ W,
                                              _Float16* __restrict__ Whi,
                                              _Float16* __restrict__ Wlo,
                                              float* __restrict__ imp) {
  const int idx = blockIdx.x * 256 + threadIdx.x;   // 0 .. 262143
  if (idx < NE) imp[idx] = 0.f;
  const int j    = idx & 7;
  const int lane = (idx >> 3) & 63;
  const int nt   = (idx >> 9) & 3;
  const int ksg  = idx >> 11;                        // 0..127
  const int e = nt * 16 + (lane & 15);
  const int k = ksg * 32 + (lane >> 4) * 8 + j;
  const float w = W[(size_t)e * NK + k];
  const _Float16 wh = (_Float16)w;
  const _Float16 wl = (_Float16)(w - (float)wh);
  Whi[idx] = wh;
  Wlo[idx] = wl;
}

// ---------------------------------------------------------------------------
// Kernel 1: partial logits via MFMA f16 hi/lo split (fp32-equivalent).
// grid = 512 blocks (64 M-groups x 8 K-segments), block = 256 (4 waves).
// Wave wv: M-tile mt = mtg*4+wv -> TWO 16-row tiles (rows mt*32 .. mt*32+32),
// all 64 experts (4 N-tiles), Kseg = 512. The two M-tiles SHARE B-fragments
// (halves B L2 traffic vs round 4); 4 waves/block share a K-segment (L1 hits).
// No LDS, no barriers; acc = 8 x f32x4.
// D layout (verified round 4, absmax 0): col = lane&15, row = (lane>>4)*4+reg.
// ---------------------------------------------------------------------------
__global__ __launch_bounds__(256) void k_gemm(const float* __restrict__ x,
                                              const _Float16* __restrict__ Whi,
                                              const _Float16* __restrict__ Wlo,
                                              float* __restrict__ part) {
  const int tid  = threadIdx.x;
  const int lane = tid & 63;
  const int wv   = tid >> 6;           // 0..3
  const int mtg  = blockIdx.x >> 3;    // 0..63
  const int seg  = blockIdx.x & 7;     // K-segment
  const int mt   = mtg * 4 + wv;       // 0..255 (32-row M-tile)
  const int l15  = lane & 15;
  const int lhi  = lane >> 4;
  const int rbase = mt * 32;
  const int k0    = seg * 512;

  const float* __restrict__ xp0 = x + (size_t)(rbase + l15) * NK + k0 + lhi * 8;
  const float* __restrict__ xp1 = xp0 + (size_t)16 * NK;

  f32x4 acc0[4], acc1[4];
#pragma unroll
  for (int nt = 0; nt < 4; ++nt) {
    acc0[nt] = (f32x4){0.f, 0.f, 0.f, 0.f};
    acc1[nt] = (f32x4){0.f, 0.f, 0.f, 0.f};
  }

#pragma unroll 2
  for (int ks = 0; ks < 16; ++ks) {   // 16 K-steps of 32
    // ---- A fragments for both M-tiles: 8 f32 each -> (hi, lo) f16x8 ----
    const float4 a0 = *(const float4*)(xp0 + ks * 32);
    const float4 a1 = *(const float4*)(xp0 + ks * 32 + 4);
    const float4 b0 = *(const float4*)(xp1 + ks * 32);
    const float4 b1 = *(const float4*)(xp1 + ks * 32 + 4);
    f16x8 ah, al, bh, bl;
    ah[0] = (_Float16)a0.x; al[0] = (_Float16)(a0.x - (float)ah[0]);
    ah[1] = (_Float16)a0.y; al[1] = (_Float16)(a0.y - (float)ah[1]);
    ah[2] = (_Float16)a0.z; al[2] = (_Float16)(a0.z - (float)ah[2]);
    ah[3] = (_Float16)a0.w; al[3] = (_Float16)(a0.w - (float)ah[3]);
    ah[4] = (_Float16)a1.x; al[4] = (_Float16)(a1.x - (float)ah[4]);
    ah[5] = (_Float16)a1.y; al[5] = (_Float16)(a1.y - (float)ah[5]);
    ah[6] = (_Float16)a1.z; al[6] = (_Float16)(a1.z - (float)ah[6]);
    ah[7] = (_Float16)a1.w; al[7] = (_Float16)(a1.w - (float)ah[7]);
    bh[0] = (_Float16)b0.x; bl[0] = (_Float16)(b0.x - (float)bh[0]);
    bh[1] = (_Float16)b0.y; bl[1] = (_Float16)(b0.y - (float)bh[1]);
    bh[2] = (_Float16)b0.z; bl[2] = (_Float16)(b0.z - (float)bh[2]);
    bh[3] = (_Float16)b0.w; bl[3] = (_Float16)(b0.w - (float)bh[3]);
    bh[4] = (_Float16)b1.x; bl[4] = (_Float16)(b1.x - (float)bh[4]);
    bh[5] = (_Float16)b1.y; bl[5] = (_Float16)(b1.y - (float)bh[5]);
    bh[6] = (_Float16)b1.z; bl[6] = (_Float16)(b1.z - (float)bh[6]);
    bh[7] = (_Float16)b1.w; bl[7] = (_Float16)(b1.w - (float)bh[7]);

    // ---- B fragments (shared by both M-tiles), fragment-linear ----
    const int gk = seg * 16 + ks;     // global 32-k group, 0..127
    const size_t boff = ((size_t)(gk * 4) * 64 + lane) * 8;
    f16x8 wh_[4], wl_[4];
#pragma unroll
    for (int nt = 0; nt < 4; ++nt) {
      wh_[nt] = *(const f16x8*)(Whi + boff + nt * 512);
      wl_[nt] = *(const f16x8*)(Wlo + boff + nt * 512);
    }
    // ---- 24 MFMAs (hi*hi + hi*lo + lo*hi for each M-tile) ----
#pragma unroll
    for (int nt = 0; nt < 4; ++nt) {
      acc0[nt] = __builtin_amdgcn_mfma_f32_16x16x32_f16(ah, wh_[nt], acc0[nt], 0, 0, 0);
      acc1[nt] = __builtin_amdgcn_mfma_f32_16x16x32_f16(bh, wh_[nt], acc1[nt], 0, 0, 0);
    }
#pragma unroll
    for (int nt = 0; nt < 4; ++nt) {
      acc0[nt] = __builtin_amdgcn_mfma_f32_16x16x32_f16(ah, wl_[nt], acc0[nt], 0, 0, 0);
      acc1[nt] = __builtin_amdgcn_mfma_f32_16x16x32_f16(bh, wl_[nt], acc1[nt], 0, 0, 0);
    }
#pragma unroll
    for (int nt = 0; nt < 4; ++nt) {
      acc0[nt] = __builtin_amdgcn_mfma_f32_16x16x32_f16(al, wh_[nt], acc0[nt], 0, 0, 0);
      acc1[nt] = __builtin_amdgcn_mfma_f32_16x16x32_f16(bl, wh_[nt], acc1[nt], 0, 0, 0);
    }
  }

  // ---- epilogue: D col = lane&15, row = (lane>>4)*4 + reg ----
  float* dst0 = part + ((size_t)seg * NROWS + rbase) * NE;
  float* dst1 = dst0 + (size_t)16 * NE;
#pragma unroll
  for (int nt = 0; nt < 4; ++nt)
#pragma unroll
    for (int r = 0; r < 4; ++r) {
      dst0[(size_t)(lhi * 4 + r) * NE + nt * 16 + l15] = acc0[nt][r];
      dst1[(size_t)(lhi * 4 + r) * NE + nt * 16 + l15] = acc1[nt][r];
    }
}

// ---------------------------------------------------------------------------
// Kernel 2: sum 8 K-segment partials (pairwise tree) -> softmax over 64
// experts (lane = expert) -> stable top-2 (lowest-index tie-break) -> renorm
// softmax -> outputs; importance per block, one atomicAdd per expert.
// ---------------------------------------------------------------------------
__global__ __launch_bounds__(256) void k_softmax(const float* __restrict__ part,
                                                 float* __restrict__ out,
                                                 float* __restrict__ imp) {
  __shared__ float simp[4][64];
  const int tid  = threadIdx.x;
  const int lane = tid & 63;
  const int wv   = tid >> 6;
  const int rbase = blockIdx.x * 32 + wv * 8;
  float impacc = 0.f;

  for (int i = 0; i < 8; ++i) {
    const int row = rbase + i;
    float v[NSEG];
#pragma unroll
    for (int s = 0; s < NSEG; ++s)
      v[s] = part[((size_t)s * NROWS + row) * NE + lane];
    const float lg = (((v[0] + v[1]) + (v[2] + v[3])) +
                      ((v[4] + v[5]) + (v[6] + v[7])));

    float m = lg;
#pragma unroll
    for (int d = 1; d < 64; d <<= 1) m = fmaxf(m, __shfl_xor(m, d));
    float p = expf(lg - m);
    float s = p;
#pragma unroll
    for (int d = 1; d < 64; d <<= 1) s += __shfl_xor(s, d);
    const float gate = p / s;
    impacc += gate;

    const unsigned long long key =
        ((unsigned long long)__float_as_uint(gate) << 32) | (unsigned)(63 - lane);
    unsigned long long k1 = key;
#pragma unroll
    for (int d = 1; d < 64; d <<= 1) {
      unsigned long long o = __shfl_xor(k1, d);
      if (o > k1) k1 = o;
    }
    const int e1 = 63 - (int)(k1 & 63ull);
    unsigned long long k2 = (lane == e1) ? 0ull : key;
#pragma unroll
    for (int d = 1; d < 64; d <<= 1) {
      unsigned long long o = __shfl_xor(k2, d);
      if (o > k2) k2 = o;
    }
    const int e2 = 63 - (int)(k2 & 63ull);

    if (lane == 0) {
      const float g1 = __uint_as_float((unsigned)(k1 >> 32));
      const float g2 = __uint_as_float((unsigned)(k2 >> 32));
      const float tt  = expf(g2 - g1);          // g1 >= g2
      const float inv = 1.f / (1.f + tt);
      out[(size_t)row * 2]     = inv;
      out[(size_t)row * 2 + 1] = tt * inv;
      out[(size_t)NROWS * 2 + row * 2]     = (float)e1;
      out[(size_t)NROWS * 2 + row * 2 + 1] = (float)e2;
    }
  }

  simp[wv][lane] = impacc;
  __syncthreads();
  if (tid < NE) {
    const float v = simp[0][tid] + simp[1][tid] + simp[2][tid] + simp[3][tid];
    atomicAdd(&imp[tid], v);
  }
}

// ---------------------------------------------------------------------------
// Kernel 3: aux loss from importance vector (1 wave).
// ---------------------------------------------------------------------------
__global__ void k_aux(const float* __restrict__ imp, float* __restrict__ out) {
  const int lane = threadIdx.x;  // 64 threads
  const float v = imp[lane];
  float s = v;
#pragma unroll
  for (int d = 1; d < 64; d <<= 1) s += __shfl_xor(s, d);
  const float mean = s / 64.f;
  const float dv = v - mean;
  float sq = dv * dv;
#pragma unroll
  for (int d = 1; d < 64; d <<= 1) sq += __shfl_xor(sq, d);
  const float stdv = sqrtf(sq / 63.f);  // unbiased (E-1)
  const float r = stdv / (mean + 1e-6f);
  if (lane == 0) out[(size_t)NROWS * 4] = r * r;  // d_out[32768]
}

// ---------------------------------------------------------------------------
extern "C" void kernel_launch(void* const* d_in, const int* in_sizes, int n_in,
                              void* d_out, int out_size, void* d_ws, size_t ws_size,
                              hipStream_t stream) {
  const float* x = (const float*)d_in[0];
  const float* W = (const float*)d_in[1];
  float* out  = (float*)d_out;
  float* part = (float*)d_ws;                           // 8*8192*64 f32 = 16 MB
  _Float16* Whi = (_Float16*)(part + (size_t)NSEG * NROWS * NE);  // 512 KB
  _Float16* Wlo = Whi + (size_t)NE * NK;                          // 512 KB
  float* imp  = (float*)(Wlo + (size_t)NE * NK);                  // 64 f32

  hipLaunchKernelGGL(k_prep,    dim3(1024), dim3(256), 0, stream, W, Whi, Wlo, imp);
  hipLaunchKernelGGL(k_gemm,    dim3(512),  dim3(256), 0, stream, x, Whi, Wlo, part);
  hipLaunchKernelGGL(k_softmax, dim3(256),  dim3(256), 0, stream, part, out, imp);
  hipLaunchKernelGGL(k_aux,     dim3(1),    dim3(64),  0, stream, imp, out);
}

// Round 6
// 49.336 us; speedup vs baseline: 5.6711x; 1.2244x over previous
//
#include <hip/hip_runtime.h>
#include <math.h>

#define NROWS 8192
#define NK    4096
#define NE    64
#define NWV   8     // waves per block = K segments of 512

typedef _Float16 f16x8 __attribute__((ext_vector_type(8)));  // 4 VGPRs
typedef float    f32x4 __attribute__((ext_vector_type(4)));

// ---------------------------------------------------------------------------
// Kernel 0: arrange W into MFMA-fragment-linear f16 hi/lo arrays + zero imp.
// Element ((ksg*4 + nt)*64 + lane)*8 + j  holds
//   f16( W[nt*16 + (lane&15)][ksg*32 + (lane>>4)*8 + j] ),  ksg = 0..127.
// (verified rounds 4-5, absmax 0)
// ---------------------------------------------------------------------------
__global__ __launch_bounds__(256) void k_prep(const float* __restrict__ W,
                                              _Float16* __restrict__ Whi,
                                              _Float16* __restrict__ Wlo,
                                              float* __restrict__ imp) {
  const int idx = blockIdx.x * 256 + threadIdx.x;   // 0 .. 262143
  if (idx < NE) imp[idx] = 0.f;
  const int j    = idx & 7;
  const int lane = (idx >> 3) & 63;
  const int nt   = (idx >> 9) & 3;
  const int ksg  = idx >> 11;                        // 0..127
  const int e = nt * 16 + (lane & 15);
  const int k = ksg * 32 + (lane >> 4) * 8 + j;
  const float w = W[(size_t)e * NK + k];
  const _Float16 wh = (_Float16)w;
  const _Float16 wl = (_Float16)(w - (float)wh);
  Whi[idx] = wh;
  Wlo[idx] = wl;
}

// ---------------------------------------------------------------------------
// Kernel 1 (FUSED): 32 rows x full K per block; GEMM partials -> LDS ->
// tree-reduce -> softmax/top-2/renorm -> final outputs + importance atomics.
// grid = 256 (1 block/CU), block = 512 (8 waves).
// Wave wv: TWO 16-row M-tiles (rows blk*32 .. +32) x K-seg [wv*512, +512),
// B-fragments shared between the M-tiles (round-5 structure, absmax 0).
// Partials never touch HBM (round 5: 16 MB write + 16 MB read eliminated).
// ---------------------------------------------------------------------------
__global__ __launch_bounds__(512, 1) void k_fused(const float* __restrict__ x,
                                                  const _Float16* __restrict__ Whi,
                                                  const _Float16* __restrict__ Wlo,
                                                  float* __restrict__ out,
                                                  float* __restrict__ imp) {
  __shared__ float plds[NWV][32][64];   // 64 KB partial logits
  __shared__ float logit[32][64];       // 8 KB reduced logits
  __shared__ float simp[NWV][64];       // 2 KB importance partials

  const int tid  = threadIdx.x;
  const int lane = tid & 63;
  const int wv   = __builtin_amdgcn_readfirstlane(tid >> 6);  // 0..7 = K-seg
  const int l15  = lane & 15;
  const int lhi  = lane >> 4;
  const int rbase = blockIdx.x * 32;
  const int k0    = wv * 512;

  const float* __restrict__ xp0 = x + (size_t)(rbase + l15) * NK + k0 + lhi * 8;
  const float* __restrict__ xp1 = xp0 + (size_t)16 * NK;

  f32x4 acc0[4], acc1[4];
#pragma unroll
  for (int nt = 0; nt < 4; ++nt) {
    acc0[nt] = (f32x4){0.f, 0.f, 0.f, 0.f};
    acc1[nt] = (f32x4){0.f, 0.f, 0.f, 0.f};
  }

#pragma unroll 2
  for (int ks = 0; ks < 16; ++ks) {   // 16 K-steps of 32
    const float4 a0 = *(const float4*)(xp0 + ks * 32);
    const float4 a1 = *(const float4*)(xp0 + ks * 32 + 4);
    const float4 b0 = *(const float4*)(xp1 + ks * 32);
    const float4 b1 = *(const float4*)(xp1 + ks * 32 + 4);
    f16x8 ah, al, bh, bl;
    ah[0] = (_Float16)a0.x; al[0] = (_Float16)(a0.x - (float)ah[0]);
    ah[1] = (_Float16)a0.y; al[1] = (_Float16)(a0.y - (float)ah[1]);
    ah[2] = (_Float16)a0.z; al[2] = (_Float16)(a0.z - (float)ah[2]);
    ah[3] = (_Float16)a0.w; al[3] = (_Float16)(a0.w - (float)ah[3]);
    ah[4] = (_Float16)a1.x; al[4] = (_Float16)(a1.x - (float)ah[4]);
    ah[5] = (_Float16)a1.y; al[5] = (_Float16)(a1.y - (float)ah[5]);
    ah[6] = (_Float16)a1.z; al[6] = (_Float16)(a1.z - (float)ah[6]);
    ah[7] = (_Float16)a1.w; al[7] = (_Float16)(a1.w - (float)ah[7]);
    bh[0] = (_Float16)b0.x; bl[0] = (_Float16)(b0.x - (float)bh[0]);
    bh[1] = (_Float16)b0.y; bl[1] = (_Float16)(b0.y - (float)bh[1]);
    bh[2] = (_Float16)b0.z; bl[2] = (_Float16)(b0.z - (float)bh[2]);
    bh[3] = (_Float16)b0.w; bl[3] = (_Float16)(b0.w - (float)bh[3]);
    bh[4] = (_Float16)b1.x; bl[4] = (_Float16)(b1.x - (float)bh[4]);
    bh[5] = (_Float16)b1.y; bl[5] = (_Float16)(b1.y - (float)bh[5]);
    bh[6] = (_Float16)b1.z; bl[6] = (_Float16)(b1.z - (float)bh[6]);
    bh[7] = (_Float16)b1.w; bl[7] = (_Float16)(b1.w - (float)bh[7]);

    const int gk = wv * 16 + ks;      // global 32-k group, 0..127
    const size_t boff = ((size_t)(gk * 4) * 64 + lane) * 8;
    f16x8 wh_[4], wl_[4];
#pragma unroll
    for (int nt = 0; nt < 4; ++nt) {
      wh_[nt] = *(const f16x8*)(Whi + boff + nt * 512);
      wl_[nt] = *(const f16x8*)(Wlo + boff + nt * 512);
    }
#pragma unroll
    for (int nt = 0; nt < 4; ++nt) {
      acc0[nt] = __builtin_amdgcn_mfma_f32_16x16x32_f16(ah, wh_[nt], acc0[nt], 0, 0, 0);
      acc1[nt] = __builtin_amdgcn_mfma_f32_16x16x32_f16(bh, wh_[nt], acc1[nt], 0, 0, 0);
    }
#pragma unroll
    for (int nt = 0; nt < 4; ++nt) {
      acc0[nt] = __builtin_amdgcn_mfma_f32_16x16x32_f16(ah, wl_[nt], acc0[nt], 0, 0, 0);
      acc1[nt] = __builtin_amdgcn_mfma_f32_16x16x32_f16(bh, wl_[nt], acc1[nt], 0, 0, 0);
    }
#pragma unroll
    for (int nt = 0; nt < 4; ++nt) {
      acc0[nt] = __builtin_amdgcn_mfma_f32_16x16x32_f16(al, wh_[nt], acc0[nt], 0, 0, 0);
      acc1[nt] = __builtin_amdgcn_mfma_f32_16x16x32_f16(bl, wh_[nt], acc1[nt], 0, 0, 0);
    }
  }

  // ---- epilogue to LDS: D col = lane&15, row = (lane>>4)*4 + reg ----
#pragma unroll
  for (int nt = 0; nt < 4; ++nt)
#pragma unroll
    for (int r = 0; r < 4; ++r) {
      plds[wv][lhi * 4 + r][nt * 16 + l15]      = acc0[nt][r];
      plds[wv][16 + lhi * 4 + r][nt * 16 + l15] = acc1[nt][r];
    }
  __syncthreads();

  // ---- 8-seg pairwise tree reduce (same tree as round 5 -> bit-identical) --
#pragma unroll
  for (int i = 0; i < 4; ++i) {
    const int elem = tid + i * 512;      // 0..2047
    const int row  = elem >> 6;
    const int col  = elem & 63;
    const float s01 = plds[0][row][col] + plds[1][row][col];
    const float s23 = plds[2][row][col] + plds[3][row][col];
    const float s45 = plds[4][row][col] + plds[5][row][col];
    const float s67 = plds[6][row][col] + plds[7][row][col];
    logit[row][col] = ((s01 + s23) + (s45 + s67));
  }
  __syncthreads();

  // ---- softmax/top-2/renorm: wave wv handles rows wv*4 .. +4 --------------
  float impacc = 0.f;
#pragma unroll 1
  for (int i = 0; i < 4; ++i) {
    const int rl  = wv * 4 + i;
    const int row = rbase + rl;
    const float lg = logit[rl][lane];

    float m = lg;
#pragma unroll
    for (int d = 1; d < 64; d <<= 1) m = fmaxf(m, __shfl_xor(m, d));
    float p = expf(lg - m);
    float s = p;
#pragma unroll
    for (int d = 1; d < 64; d <<= 1) s += __shfl_xor(s, d);
    const float gate = p / s;
    impacc += gate;

    const unsigned long long key =
        ((unsigned long long)__float_as_uint(gate) << 32) | (unsigned)(63 - lane);
    unsigned long long k1 = key;
#pragma unroll
    for (int d = 1; d < 64; d <<= 1) {
      unsigned long long o = __shfl_xor(k1, d);
      if (o > k1) k1 = o;
    }
    const int e1 = 63 - (int)(k1 & 63ull);
    unsigned long long k2 = (lane == e1) ? 0ull : key;
#pragma unroll
    for (int d = 1; d < 64; d <<= 1) {
      unsigned long long o = __shfl_xor(k2, d);
      if (o > k2) k2 = o;
    }
    const int e2 = 63 - (int)(k2 & 63ull);

    if (lane == 0) {
      const float g1 = __uint_as_float((unsigned)(k1 >> 32));
      const float g2 = __uint_as_float((unsigned)(k2 >> 32));
      const float tt  = expf(g2 - g1);          // g1 >= g2
      const float inv = 1.f / (1.f + tt);
      out[(size_t)row * 2]     = inv;
      out[(size_t)row * 2 + 1] = tt * inv;
      out[(size_t)NROWS * 2 + row * 2]     = (float)e1;
      out[(size_t)NROWS * 2 + row * 2 + 1] = (float)e2;
    }
  }
  simp[wv][lane] = impacc;
  __syncthreads();

  if (tid < NE) {
    const float v = (((simp[0][tid] + simp[1][tid]) + (simp[2][tid] + simp[3][tid])) +
                     ((simp[4][tid] + simp[5][tid]) + (simp[6][tid] + simp[7][tid])));
    atomicAdd(&imp[tid], v);
  }
}

// ---------------------------------------------------------------------------
// Kernel 2: aux loss from importance vector (1 wave).
// ---------------------------------------------------------------------------
__global__ void k_aux(const float* __restrict__ imp, float* __restrict__ out) {
  const int lane = threadIdx.x;  // 64 threads
  const float v = imp[lane];
  float s = v;
#pragma unroll
  for (int d = 1; d < 64; d <<= 1) s += __shfl_xor(s, d);
  const float mean = s / 64.f;
  const float dv = v - mean;
  float sq = dv * dv;
#pragma unroll
  for (int d = 1; d < 64; d <<= 1) sq += __shfl_xor(sq, d);
  const float stdv = sqrtf(sq / 63.f);  // unbiased (E-1)
  const float r = stdv / (mean + 1e-6f);
  if (lane == 0) out[(size_t)NROWS * 4] = r * r;  // d_out[32768]
}

// ---------------------------------------------------------------------------
extern "C" void kernel_launch(void* const* d_in, const int* in_sizes, int n_in,
                              void* d_out, int out_size, void* d_ws, size_t ws_size,
                              hipStream_t stream) {
  const float* x = (const float*)d_in[0];
  const float* W = (const float*)d_in[1];
  float* out  = (float*)d_out;
  _Float16* Whi = (_Float16*)d_ws;                 // 512 KB
  _Float16* Wlo = Whi + (size_t)NE * NK;           // 512 KB
  float* imp  = (float*)(Wlo + (size_t)NE * NK);   // 64 f32

  hipLaunchKernelGGL(k_prep,  dim3(1024), dim3(256), 0, stream, W, Whi, Wlo, imp);
  hipLaunchKernelGGL(k_fused, dim3(256),  dim3(512), 0, stream, x, Whi, Wlo, out, imp);
  hipLaunchKernelGGL(k_aux,   dim3(1),    dim3(64),  0, stream, imp, out);
}